// Round 1
// baseline (285.297 us; speedup 1.0000x reference)
//
#include <hip/hip_runtime.h>
#include <math.h>

#define NB 8
#define PP 4096
#define MM 2048
#define QCHUNK 1024

// ---------------- log2 sum over likelihoods -> ws[2] ----------------
__global__ void log2sum_kernel(const float* __restrict__ lik, float* __restrict__ ws, int total) {
    int tid = blockIdx.x * blockDim.x + threadIdx.x;
    float s = 0.f;
    for (int i = tid; i < total; i += gridDim.x * blockDim.x)
        s += log2f(lik[i]);
    #pragma unroll
    for (int off = 32; off > 0; off >>= 1)
        s += __shfl_down(s, off, 64);
    __shared__ float red[4];
    int lane = threadIdx.x & 63, wid = threadIdx.x >> 6;
    if (lane == 0) red[wid] = s;
    __syncthreads();
    if (threadIdx.x == 0) {
        float t = red[0] + red[1] + red[2] + red[3];
        atomicAdd(&ws[2], t);
    }
}

// ---------------- chamfer: sum over p of min_q d(p,q) ----------------
// grid = 2 (dir) * NB (8) * (PP/256 = 16) = 256 blocks, 256 threads.
// dir 0: a = x_hat, b = points  -> ws[0]   (cham_x numerator)
// dir 1: a = points, b = x_hat  -> ws[1]   (cham_y numerator)
__global__ void chamfer_kernel(const float* __restrict__ x, const float* __restrict__ y,
                               float* __restrict__ ws) {
    int bx = blockIdx.x;
    int dir = bx >> 7;        // 128 blocks per direction
    int rem = bx & 127;
    int n = rem >> 4;         // 16 chunks per batch
    int chunk = rem & 15;
    const float* a = dir ? y : x;
    const float* b = dir ? x : y;

    __shared__ float4 lds[QCHUNK];   // 16 KiB

    int p = chunk * 256 + (int)threadIdx.x;
    const float* ap = a + ((size_t)n * PP + p) * 3;
    float x0 = ap[0], x1 = ap[1], x2 = ap[2];
    float xs = x0 * x0 + x1 * x1 + x2 * x2;
    float nx0 = -2.f * x0, nx1 = -2.f * x1, nx2 = -2.f * x2;
    float m = INFINITY;

    const float* bn = b + (size_t)n * PP * 3;
    for (int qc = 0; qc < PP; qc += QCHUNK) {
        __syncthreads();   // previous iteration's readers done
        for (int q = (int)threadIdx.x; q < QCHUNK; q += 256) {
            const float* bp = bn + (size_t)(qc + q) * 3;
            float y0 = bp[0], y1 = bp[1], y2 = bp[2];
            lds[q] = make_float4(y0, y1, y2, y0 * y0 + y1 * y1 + y2 * y2);
        }
        __syncthreads();
        #pragma unroll 8
        for (int q = 0; q < QCHUNK; ++q) {
            float4 v = lds[q];
            // d = xs + ys - 2*(x.y)  (same formula as reference)
            float d = fmaf(nx0, v.x, fmaf(nx1, v.y, fmaf(nx2, v.z, xs + v.w)));
            m = fminf(m, d);
        }
    }

    // block-sum of per-thread mins -> atomicAdd
    float s = m;
    #pragma unroll
    for (int off = 32; off > 0; off >>= 1)
        s += __shfl_down(s, off, 64);
    __shared__ float red[4];
    int lane = threadIdx.x & 63, wid = threadIdx.x >> 6;
    if (lane == 0) red[wid] = s;
    __syncthreads();
    if (threadIdx.x == 0)
        atomicAdd(&ws[dir], red[0] + red[1] + red[2] + red[3]);
}

// ---------------- finalize the 5 scalar outputs ----------------
__global__ void finalize_kernel(const float* __restrict__ ws, float* __restrict__ out) {
    if (threadIdx.x == 0) {
        float cham_x = ws[0] / (float)(NB * PP);
        float cham_y = ws[1] / (float)(NB * PP);
        float rec = cham_x + cham_y;
        float bit_y = ws[2] / (-(float)NB);
        float bpp = bit_y / (float)PP;
        out[0] = bpp + 1.0f * rec;  // loss (LMBDA = 1)
        out[1] = bpp;               // bpp_loss
        out[2] = rec;               // rec_loss
        out[3] = bit_y;             // bit_loss
        out[4] = bpp;               // bpp_y
    }
}

extern "C" void kernel_launch(void* const* d_in, const int* in_sizes, int n_in,
                              void* d_out, int out_size, void* d_ws, size_t ws_size,
                              hipStream_t stream) {
    const float* x_hat  = (const float*)d_in[0];
    const float* points = (const float*)d_in[1];
    const float* lik    = (const float*)d_in[2];
    float* out = (float*)d_out;
    float* ws  = (float*)d_ws;

    hipMemsetAsync(ws, 0, 3 * sizeof(float), stream);
    log2sum_kernel<<<32, 256, 0, stream>>>(lik, ws, NB * MM);
    chamfer_kernel<<<256, 256, 0, stream>>>(x_hat, points, ws);
    finalize_kernel<<<1, 64, 0, stream>>>(ws, out);
}

// Round 2
// 40.143 us; speedup vs baseline: 7.1070x; 7.1070x over previous
//
#include <hip/hip_runtime.h>
#include <math.h>

#define NB 8
#define PP 4096
#define MM 2048
#define DIRS 2

#define PCHUNK 1024            // p's per block (256 threads x 4)
#define NPBLK  (PP / PCHUNK)   // 4
#define QSLICES 16
#define QS (PP / QSLICES)      // 256 q's per block

#define NMIN (DIRS * NB * PP)  // 65536 partial-min slots

// monotone float <-> uint encoding (unsigned compare == float compare)
__device__ __forceinline__ unsigned fenc(float f) {
    unsigned u = __float_as_uint(f);
    return (u & 0x80000000u) ? ~u : (u | 0x80000000u);
}
__device__ __forceinline__ float fdec(unsigned k) {
    return __uint_as_float((k & 0x80000000u) ? (k & 0x7FFFFFFFu) : ~k);
}

// ---------------- log2 sum over likelihoods -> wssum[2] ----------------
__global__ void log2sum_kernel(const float* __restrict__ lik, float* __restrict__ wssum, int total) {
    int tid = blockIdx.x * blockDim.x + threadIdx.x;
    float s = 0.f;
    for (int i = tid; i < total; i += gridDim.x * blockDim.x)
        s += log2f(lik[i]);
    #pragma unroll
    for (int off = 32; off > 0; off >>= 1)
        s += __shfl_down(s, off, 64);
    __shared__ float red[4];
    int lane = threadIdx.x & 63, wid = threadIdx.x >> 6;
    if (lane == 0) red[wid] = s;
    __syncthreads();
    if (threadIdx.x == 0)
        atomicAdd(&wssum[2], red[0] + red[1] + red[2] + red[3]);
}

// ---------------- chamfer partial mins ----------------
// grid = DIRS * NB * NPBLK * QSLICES = 2*8*4*16 = 1024 blocks of 256 threads.
// Each thread owns 4 p-points, scans a 256-q slice staged in LDS, then
// atomicMin's the encoded (min + xs) into wsmin[dir*NB*PP + n*PP + p].
__global__ __launch_bounds__(256, 4) void chamfer_kernel(const float* __restrict__ x,
                                                         const float* __restrict__ y,
                                                         unsigned* __restrict__ wsmin) {
    int bx = blockIdx.x;
    int qs  = bx & (QSLICES - 1); bx >>= 4;
    int pc  = bx & (NPBLK - 1);   bx >>= 2;
    int n   = bx & 7;             bx >>= 3;
    int dir = bx;
    const float* a = dir ? y : x;
    const float* b = dir ? x : y;
    const float* an = a + (size_t)n * PP * 3;
    const float* bn = b + (size_t)n * PP * 3;

    __shared__ float4 lds[QS];   // 4 KiB: {-2*y0, -2*y1, -2*y2, |y|^2}
    int t = threadIdx.x;
    {
        int q = qs * QS + t;     // QS == blockDim.x == 256
        const float* bp = bn + (size_t)q * 3;
        float y0 = bp[0], y1 = bp[1], y2 = bp[2];
        lds[t] = make_float4(-2.f * y0, -2.f * y1, -2.f * y2,
                             y0 * y0 + y1 * y1 + y2 * y2);
    }

    float X0[4], X1[4], X2[4], XS[4], M[4];
    #pragma unroll
    for (int i = 0; i < 4; ++i) {
        int p = pc * PCHUNK + i * 256 + t;
        const float* ap = an + (size_t)p * 3;
        X0[i] = ap[0]; X1[i] = ap[1]; X2[i] = ap[2];
        XS[i] = X0[i] * X0[i] + X1[i] * X1[i] + X2[i] * X2[i];
        M[i] = INFINITY;
    }
    __syncthreads();

    #pragma unroll 4
    for (int q = 0; q < QS; ++q) {
        float4 v = lds[q];
        #pragma unroll
        for (int i = 0; i < 4; ++i) {
            // ys - 2*x.y  (xs added after the min — constant w.r.t. q)
            float d = fmaf(X0[i], v.x, fmaf(X1[i], v.y, fmaf(X2[i], v.z, v.w)));
            M[i] = fminf(M[i], d);
        }
    }

    #pragma unroll
    for (int i = 0; i < 4; ++i) {
        int p = pc * PCHUNK + i * 256 + t;
        atomicMin(&wsmin[((size_t)dir * NB + n) * PP + p], fenc(M[i] + XS[i]));
    }
}

// ---------------- reduce mins -> wssum[0], wssum[1] ----------------
__global__ void reduce_kernel(const unsigned* __restrict__ wsmin, float* __restrict__ wssum) {
    int tid = blockIdx.x * blockDim.x + threadIdx.x;
    float s0 = 0.f, s1 = 0.f;
    for (int i = tid; i < NMIN; i += gridDim.x * blockDim.x) {
        float v = fdec(wsmin[i]);
        if (i < NB * PP) s0 += v; else s1 += v;
    }
    #pragma unroll
    for (int off = 32; off > 0; off >>= 1) {
        s0 += __shfl_down(s0, off, 64);
        s1 += __shfl_down(s1, off, 64);
    }
    __shared__ float r0[4], r1[4];
    int lane = threadIdx.x & 63, wid = threadIdx.x >> 6;
    if (lane == 0) { r0[wid] = s0; r1[wid] = s1; }
    __syncthreads();
    if (threadIdx.x == 0) {
        atomicAdd(&wssum[0], r0[0] + r0[1] + r0[2] + r0[3]);
        atomicAdd(&wssum[1], r1[0] + r1[1] + r1[2] + r1[3]);
    }
}

// ---------------- finalize the 5 scalar outputs ----------------
__global__ void finalize_kernel(const float* __restrict__ wssum, float* __restrict__ out) {
    if (threadIdx.x == 0) {
        float cham_x = wssum[0] / (float)(NB * PP);
        float cham_y = wssum[1] / (float)(NB * PP);
        float rec = cham_x + cham_y;
        float bit_y = wssum[2] / (-(float)NB);
        float bpp = bit_y / (float)PP;
        out[0] = bpp + 1.0f * rec;  // loss (LMBDA = 1)
        out[1] = bpp;               // bpp_loss
        out[2] = rec;               // rec_loss
        out[3] = bit_y;             // bit_loss
        out[4] = bpp;               // bpp_y
    }
}

extern "C" void kernel_launch(void* const* d_in, const int* in_sizes, int n_in,
                              void* d_out, int out_size, void* d_ws, size_t ws_size,
                              hipStream_t stream) {
    const float* x_hat  = (const float*)d_in[0];
    const float* points = (const float*)d_in[1];
    const float* lik    = (const float*)d_in[2];
    float* out = (float*)d_out;
    unsigned* wsmin = (unsigned*)d_ws;
    float* wssum = (float*)d_ws + NMIN;

    hipMemsetAsync(wsmin, 0xFF, NMIN * sizeof(unsigned), stream);  // +inf keys
    hipMemsetAsync(wssum, 0, 3 * sizeof(float), stream);
    log2sum_kernel<<<32, 256, 0, stream>>>(lik, wssum, NB * MM);
    chamfer_kernel<<<DIRS * NB * NPBLK * QSLICES, 256, 0, stream>>>(x_hat, points, wsmin);
    reduce_kernel<<<64, 256, 0, stream>>>(wsmin, wssum);
    finalize_kernel<<<1, 64, 0, stream>>>(wssum, out);
}